// Round 7
// baseline (157.824 us; speedup 1.0000x reference)
//
#include <hip/hip_runtime.h>
#include <hip/hip_bf16.h>

// Problem constants (fixed by reference)
#define B_    4
#define Qn_   2048
#define S_    21760   // 128*128 + 64*64 + 32*32 + 16*16

typedef short  bfx4    __attribute__((ext_vector_type(4)));
typedef short  short8  __attribute__((ext_vector_type(8)));
typedef float  floatx4 __attribute__((ext_vector_type(4)));

__device__ __forceinline__ unsigned short f2bf(float f) {
    unsigned int u = __builtin_bit_cast(unsigned int, f);
    u += 0x7fffu + ((u >> 16) & 1u);   // round-to-nearest-even
    return (unsigned short)(u >> 16);
}
__device__ __forceinline__ float bf2f(unsigned short h) {
    unsigned int u = ((unsigned int)h) << 16;
    return __builtin_bit_cast(float, u);
}

// ---------------------------------------------------------------------------
// Prep: cast+transpose weights to bf16 NxK, concat off|attn, concat biases.
// ---------------------------------------------------------------------------
__global__ __launch_bounds__(896) void prep_w(
        const float* __restrict__ Wv, const float* __restrict__ Wo,
        const float* __restrict__ Woff, const float* __restrict__ Wattn,
        const float* __restrict__ boff, const float* __restrict__ battn,
        short* __restrict__ Wvt, short* __restrict__ Wot,
        short* __restrict__ Wcat, float* __restrict__ bcat) {
    const int k = blockIdx.x;      // 0..255
    const int t = threadIdx.x;
    if (t < 256) {
        Wvt[t * 256 + k] = (short)f2bf(Wv[k * 256 + t]);
    } else if (t < 512) {
        const int n = t - 256;
        Wot[n * 256 + k] = (short)f2bf(Wo[k * 256 + n]);
    } else {
        const int n = t - 512;     // 0..383
        const float w = (n < 256) ? Woff[k * 256 + n] : Wattn[k * 128 + (n - 256)];
        Wcat[n * 256 + k] = (short)f2bf(w);
    }
    if (blockIdx.x == 0 && t < 384)
        bcat[t] = (t < 256) ? boff[t] : battn[t - 256];
}

// ---------------------------------------------------------------------------
// Persistent pipelined GEMM: C[M x Ntot] = A[M x 256] @ B[256 x Ntot] + bias
//   Grid-stride over BM=64 row-tiles; cross-tile pipeline: while tile t's
//   K-loop runs, tile (t+gridDim.x)'s A-loads are in flight (reg staging).
//   Block: 64 rows x WN*64 cols, WN waves; wave = 64x64 (4x4 frags).
//   A in LDS (bf16, 16B-chunk XOR swizzle: chunk ^= row&7), B straight from
//   L2 (weights resident), B 2-deep / A-frag 1-deep prefetch, static indices.
//   MFMA operands SWAPPED: mfma(b, a, acc) -> lane holds 4 consecutive
//   columns of one row -> row-major vector stores.
// ---------------------------------------------------------------------------
template<int WN, int A_BF16, int OUT_F32>
__global__ __launch_bounds__(WN * 64, 2) void gemm_pipe(
        const void* __restrict__ Av, const short* __restrict__ Bt,
        const float* __restrict__ bias, void* __restrict__ Cv,
        int Ntot, int ntiles) {
    constexpr int NT  = WN * 64;
    constexpr int AIT = (2048 + NT - 1) / NT;   // 16B/32B chunks per thread
    __shared__ short As[64 * 256];              // 32 KB

    const int tid  = threadIdx.x;
    const int lane = tid & 63, wave = tid >> 6;
    const int l16  = lane & 15, lq = lane >> 4;
    const int col0 = blockIdx.y * (WN * 64) + wave * 64;

    const short* bp = Bt + (long)(col0 + l16) * 256 + lq * 8;

    // reg staging for one 64x256 A tile
    floatx4 sf0[AIT], sf1[AIT];   // f32 path
    short8  sb[AIT];              // bf16 path

    auto loadA = [&](int t) {
        const long row0 = (long)t * 64;
#pragma unroll
        for (int it = 0; it < AIT; ++it) {
            const int i = tid + it * NT;
            if (i < 2048) {
                const int r = i >> 5, c = i & 31;
                if (A_BF16) {
                    sb[it] = *(const short8*)((const short*)Av + (row0 + r) * 256 + c * 8);
                } else {
                    const float* g = (const float*)Av + (row0 + r) * 256 + c * 8;
                    sf0[it] = *(const floatx4*)g;
                    sf1[it] = *(const floatx4*)(g + 4);
                }
            }
        }
    };
    auto writeA = [&]() {
#pragma unroll
        for (int it = 0; it < AIT; ++it) {
            const int i = tid + it * NT;
            if (i < 2048) {
                const int r = i >> 5, c = i & 31;
                short8 v;
                if (A_BF16) {
                    v = sb[it];
                } else {
#pragma unroll
                    for (int j = 0; j < 4; ++j) {
                        v[j]     = (short)f2bf(sf0[it][j]);
                        v[4 + j] = (short)f2bf(sf1[it][j]);
                    }
                }
                *(short8*)&As[r * 256 + ((c ^ (r & 7)) << 3)] = v;
            }
        }
    };

    loadA(blockIdx.x);
    for (int t = blockIdx.x; t < ntiles; t += (int)gridDim.x) {
        writeA();
        __syncthreads();
        const int tn = t + (int)gridDim.x;
        if (tn < ntiles) loadA(tn);          // in flight during this tile's K-loop

        floatx4 acc[4][4];
#pragma unroll
        for (int i = 0; i < 4; ++i)
#pragma unroll
            for (int j = 0; j < 4; ++j) acc[i][j] = (floatx4){0.f, 0.f, 0.f, 0.f};

        // --- prefetch queues: B 2-deep (L2 ~200cy), A-frag 1-deep (LDS) ---
        short8 bq[3][4], aq[2][4];
#pragma unroll
        for (int nf = 0; nf < 4; ++nf) {
            bq[0][nf] = *(const short8*)(bp + nf * 4096);
            bq[1][nf] = *(const short8*)(bp + nf * 4096 + 32);
        }
#pragma unroll
        for (int mf = 0; mf < 4; ++mf) {
            const int r = mf * 16 + l16;
            aq[0][mf] = *(const short8*)&As[r * 256 + ((lq ^ (r & 7)) << 3)];
        }

#pragma unroll
        for (int kk = 0; kk < 8; ++kk) {
            if (kk + 2 < 8) {
#pragma unroll
                for (int nf = 0; nf < 4; ++nf)
                    bq[(kk + 2) % 3][nf] = *(const short8*)(bp + nf * 4096 + (kk + 2) * 32);
            }
            if (kk + 1 < 8) {
#pragma unroll
                for (int mf = 0; mf < 4; ++mf) {
                    const int r = mf * 16 + l16;
                    aq[(kk + 1) & 1][mf] =
                        *(const short8*)&As[r * 256 + ((((kk + 1) * 4 + lq) ^ (r & 7)) << 3)];
                }
            }
#pragma unroll
            for (int mf = 0; mf < 4; ++mf)
#pragma unroll
                for (int nf = 0; nf < 4; ++nf)
                    acc[mf][nf] = __builtin_amdgcn_mfma_f32_16x16x32_bf16(
                        bq[kk % 3][nf], aq[kk & 1][mf], acc[mf][nf], 0, 0, 0);
        }

        // --- epilogue: row-major vector stores ---
        const long row0 = (long)t * 64;
#pragma unroll
        for (int mf = 0; mf < 4; ++mf) {
            const long grow = row0 + mf * 16 + l16;
#pragma unroll
            for (int nf = 0; nf < 4; ++nf) {
                const int gcol = col0 + nf * 16 + lq * 4;
                const floatx4 bv4 = *(const floatx4*)(bias + gcol);
                const floatx4 v = acc[mf][nf] + bv4;
                if (OUT_F32) {
                    *(floatx4*)((float*)Cv + grow * Ntot + gcol) = v;
                } else {
                    bfx4 s;
#pragma unroll
                    for (int r = 0; r < 4; ++r) s[r] = (short)f2bf(v[r]);
                    *(bfx4*)((short*)Cv + grow * Ntot + gcol) = s;
                }
            }
        }
        __syncthreads();   // all LDS reads done before next tile's writeA
    }
}

// ---------------------------------------------------------------------------
// Sampler: softmax + deformable bilinear gather -> wv (bf16)
// 512 threads, 16 queries per block. Grid = B * (Q/16) = 512.
// ---------------------------------------------------------------------------
__global__ __launch_bounds__(512) void sampler(
        const float* __restrict__ priors,
        const int* __restrict__ shapes, const int* __restrict__ starts,
        const float* __restrict__ offattn,   // [B*Q][384]: 256 off | 128 attn logits
        const short* __restrict__ value, short* __restrict__ wv) {
    __shared__ float oa_lds[16][384];
    __shared__ float pri_lds[16][4][2];
    __shared__ int   shp_lds[4][2];
    __shared__ int   st_lds[4];

    const int tid = threadIdx.x;
    const int b   = blockIdx.x >> 7;
    const int qt  = blockIdx.x & 127;
    const long q0 = (long)qt * 16;

    const float* src = offattn + ((long)b * Qn_ + q0) * 384;
    for (int i = tid; i < 16 * 384 / 4; i += 512)
        ((floatx4*)oa_lds)[i] = ((const floatx4*)src)[i];
    if (tid < 128) ((float*)pri_lds)[tid] = priors[((long)b * Qn_ + q0) * 8 + tid];
    if (tid < 8)  ((int*)shp_lds)[tid] = shapes[tid];
    if (tid < 4)  st_lds[tid] = starts[tid];
    __syncthreads();

    if (tid < 128) {
        const int qi = tid >> 3, h = tid & 7;
        float* a = &oa_lds[qi][256 + h * 16];
        float m = a[0];
        for (int i = 1; i < 16; ++i) m = fmaxf(m, a[i]);
        float s = 0.f;
        for (int i = 0; i < 16; ++i) { float e = expf(a[i] - m); a[i] = e; s += e; }
        const float inv = 1.f / s;
        for (int i = 0; i < 16; ++i) a[i] *= inv;
    }
    __syncthreads();

    const int pairi = tid >> 2, sub = tid & 3;
    const int qi = pairi >> 3, h = pairi & 7;
    float acc[8];
#pragma unroll
    for (int j = 0; j < 8; ++j) acc[j] = 0.f;
    const short* vbase = value + (long)b * S_ * 256 + h * 32 + sub * 8;

    for (int l = 0; l < 4; ++l) {
        const int Hl = shp_lds[l][0], Wl = shp_lds[l][1];
        const int st = st_lds[l];
        const float px = pri_lds[qi][l][0], py = pri_lds[qi][l][1];
        const float invW = 1.f / (float)Wl, invH = 1.f / (float)Hl;
        for (int p = 0; p < 4; ++p) {
            const int cb = h * 16 + l * 4 + p;
            const float ox = oa_lds[qi][cb * 2], oy = oa_lds[qi][cb * 2 + 1];
            const float lx = px + ox * invW, ly = py + oy * invH;
            const float ix = lx * (float)Wl - 0.5f, iy = ly * (float)Hl - 0.5f;
            const float x0f = floorf(ix), y0f = floorf(iy);
            const int x0 = (int)x0f, y0 = (int)y0f;
            const float fx = ix - x0f, fy = iy - y0f;
            const float awv = oa_lds[qi][256 + cb];
#pragma unroll
            for (int dy = 0; dy < 2; ++dy) {
                const int yc = y0 + dy;
                if (yc < 0 || yc >= Hl) continue;
                const float wy = dy ? fy : 1.f - fy;
#pragma unroll
                for (int dx = 0; dx < 2; ++dx) {
                    const int xc = x0 + dx;
                    if (xc < 0 || xc >= Wl) continue;
                    const float wx = dx ? fx : 1.f - fx;
                    const float w = wy * wx * awv;
                    const short8 v = *(const short8*)(vbase + ((long)st + (long)yc * Wl + xc) * 256);
#pragma unroll
                    for (int j = 0; j < 8; ++j) acc[j] += w * bf2f((unsigned short)v[j]);
                }
            }
        }
    }

    short8 ov;
#pragma unroll
    for (int j = 0; j < 8; ++j) ov[j] = (short)f2bf(acc[j]);
    *(short8*)(wv + (((long)b * Qn_ + q0 + qi) * 256 + h * 32 + sub * 8)) = ov;
}

// ---------------------------------------------------------------------------
extern "C" void kernel_launch(void* const* d_in, const int* in_sizes, int n_in,
                              void* d_out, int out_size, void* d_ws, size_t ws_size,
                              hipStream_t stream) {
    const float* in_feats = (const float*)d_in[0];
    const float* priors   = (const float*)d_in[1];
    const float* sfeats   = (const float*)d_in[2];
    const int*   shapes   = (const int*)d_in[3];
    const int*   starts   = (const int*)d_in[4];
    const float* W_off    = (const float*)d_in[5];
    const float* b_off    = (const float*)d_in[6];
    const float* W_attn   = (const float*)d_in[7];
    const float* b_attn   = (const float*)d_in[8];
    const float* W_val    = (const float*)d_in[9];
    const float* b_val    = (const float*)d_in[10];
    const float* W_out    = (const float*)d_in[11];
    const float* b_out    = (const float*)d_in[12];
    float* out = (float*)d_out;

    // Workspace: Wvt 128K | Wot 128K | Wcat 192K | value 44.56M | wv 4M (short)
    //            offattn 12.58M | bcat 1.5K (f32)
    short* Wvt     = (short*)d_ws;
    short* Wot     = Wvt + 65536;
    short* Wcat    = Wot + 65536;
    short* value   = Wcat + 98304;
    short* wv      = value + (long)B_ * S_ * 256;
    float* offattn = (float*)(wv + (long)B_ * Qn_ * 256);
    float* bcat    = offattn + (long)B_ * Qn_ * 384;

    prep_w<<<256, 896, 0, stream>>>(W_val, W_out, W_off, W_attn, b_off, b_attn,
                                    Wvt, Wot, Wcat, bcat);
    // value = sample_feats @ W_val + b_val   (87040 x 256), bf16 out
    // persistent: 512 blocks, 2-3 tiles each, cross-tile pipelined
    gemm_pipe<4, 0, 0><<<dim3(512, 1), 256, 0, stream>>>(
        (const void*)sfeats, Wvt, b_val, (void*)value, 256, (B_ * S_) / 64);
    // offattn = in_feats @ [W_off|W_attn] + bcat  (8192 x 384), f32 out
    gemm_pipe<3, 0, 1><<<dim3(128, 2), 192, 0, stream>>>(
        (const void*)in_feats, Wcat, bcat, (void*)offattn, 384, (B_ * Qn_) / 64);
    // softmax + deformable sampling
    sampler<<<B_ * (Qn_ / 16), 512, 0, stream>>>(priors, shapes, starts,
                                                 offattn, value, wv);
    // out = wv @ W_out + b_out   (8192 x 256), f32 out
    gemm_pipe<2, 1, 1><<<dim3(128, 2), 128, 0, stream>>>(
        (const void*)wv, Wot, b_out, (void*)out, 256, (B_ * Qn_) / 64);
}

// Round 8
// 96.352 us; speedup vs baseline: 1.6380x; 1.6380x over previous
//
#include <hip/hip_runtime.h>
#include <hip/hip_bf16.h>

// Problem constants (fixed by reference)
#define B_    4
#define Qn_   2048
#define S_    21760   // 128*128 + 64*64 + 32*32 + 16*16

typedef short  bfx4    __attribute__((ext_vector_type(4)));
typedef short  short8  __attribute__((ext_vector_type(8)));
typedef float  floatx4 __attribute__((ext_vector_type(4)));

__device__ __forceinline__ unsigned short f2bf(float f) {
    unsigned int u = __builtin_bit_cast(unsigned int, f);
    u += 0x7fffu + ((u >> 16) & 1u);   // round-to-nearest-even
    return (unsigned short)(u >> 16);
}
__device__ __forceinline__ float bf2f(unsigned short h) {
    unsigned int u = ((unsigned int)h) << 16;
    return __builtin_bit_cast(float, u);
}

// async global->LDS, 16B per lane. lds must be WAVE-UNIFORM base (lane*16 implicit).
__device__ __forceinline__ void async16(void* lds, const void* g) {
    __builtin_amdgcn_global_load_lds(
        (const __attribute__((address_space(1))) unsigned int*)g,
        (__attribute__((address_space(3))) unsigned int*)lds, 16, 0, 0);
}

template<int N>
__device__ __forceinline__ void wait_vm_lgkm0() {
    asm volatile("s_waitcnt vmcnt(%0) lgkmcnt(0)" :: "n"(N) : "memory");
}

// ---------------------------------------------------------------------------
// Prep: cast+transpose weights to bf16 NxK, concat off|attn, concat biases.
// ---------------------------------------------------------------------------
__global__ __launch_bounds__(896) void prep_w(
        const float* __restrict__ Wv, const float* __restrict__ Wo,
        const float* __restrict__ Woff, const float* __restrict__ Wattn,
        const float* __restrict__ boff, const float* __restrict__ battn,
        short* __restrict__ Wvt, short* __restrict__ Wot,
        short* __restrict__ Wcat, float* __restrict__ bcat) {
    const int k = blockIdx.x;      // 0..255
    const int t = threadIdx.x;
    if (t < 256) {
        Wvt[t * 256 + k] = (short)f2bf(Wv[k * 256 + t]);
    } else if (t < 512) {
        const int n = t - 256;
        Wot[n * 256 + k] = (short)f2bf(Wo[k * 256 + n]);
    } else {
        const int n = t - 512;     // 0..383
        const float w = (n < 256) ? Woff[k * 256 + n] : Wattn[k * 128 + (n - 256)];
        Wcat[n * 256 + k] = (short)f2bf(w);
    }
    if (blockIdx.x == 0 && t < 384)
        bcat[t] = (t < 256) ? boff[t] : battn[t - 256];
}

// ---------------------------------------------------------------------------
// gemm_v8: C[M x 256] = A[M x 256] @ B[256 x 256] + bias.  BM=64, 4 waves.
//   2-phase K-loop (8 x BK=32) with T4 counted-vmcnt barriers:
//   - B staged via global_load_lds (4 DMA/thread/step, issued FIRST = oldest)
//   - A prefetched TWO steps ahead into 2 register sets (8 f32/thread)
//   - s_waitcnt vmcnt(VM) lgkmcnt(0) + raw s_barrier: drains the B-DMAs but
//     leaves the newest VM A-loads in flight across the barrier.
//   LDS [r][32] bf16 rows, 16B-chunk XOR swizzle (chunk ^= r&3) applied on
//   global source + ds_read (rule #21).  MFMA operands swapped -> row-major
//   vector stores (grow = mf*16+l16, gcol = wave*64+nf*16+lq*4).
// ---------------------------------------------------------------------------
template<int A_BF16, int OUT_F32>
__global__ __launch_bounds__(256) void gemm_v8(
        const void* __restrict__ Av, const short* __restrict__ Bt,
        const float* __restrict__ bias, void* __restrict__ Cv) {
    constexpr int VM = A_BF16 ? 1 : 2;   // A-loads allowed to stay in flight
    __shared__ short As[2][64 * 32];     // 8 KB
    __shared__ short Bs[2][256 * 32];    // 32 KB

    const int tid  = threadIdx.x;
    const int lane = tid & 63, wave = tid >> 6;
    const int l16  = lane & 15, lq = lane >> 4;
    const long row0 = (long)blockIdx.x * 64;
    const int  r_a = tid >> 2, c_a = tid & 3;   // A-stage: 1 chunk (16B bf16 / 32B f32)

    floatx4 sA0[2], sA1[2];
    short8  sB16[2];

    auto loadA = [&](int kk, int s) {
        if (A_BF16) {
            sB16[s] = *(const short8*)((const short*)Av + (row0 + r_a) * 256 + kk * 32 + c_a * 8);
        } else {
            const float* g = (const float*)Av + (row0 + r_a) * 256 + kk * 32 + c_a * 8;
            sA0[s] = *(const floatx4*)g;
            sA1[s] = *(const floatx4*)(g + 4);
        }
    };
    auto writeA = [&](int buf, int s) {
        short8 v;
        if (A_BF16) {
            v = sB16[s];
        } else {
#pragma unroll
            for (int j = 0; j < 4; ++j) {
                v[j]     = (short)f2bf(sA0[s][j]);
                v[4 + j] = (short)f2bf(sA1[s][j]);
            }
        }
        *(short8*)&As[buf][r_a * 32 + ((c_a ^ (r_a & 3)) << 3)] = v;
    };
    auto stageB = [&](int kk, int buf) {
#pragma unroll
        for (int c2 = 0; c2 < 4; ++c2) {
            const int idx = c2 * 256 + tid;
            const int r = idx >> 2, ch = idx & 3;
            const short* g = Bt + (long)r * 256 + kk * 32 + ((ch ^ (r & 3)) << 3);
            async16(&Bs[buf][(c2 * 256 + (wave << 6)) * 8], g);
        }
    };

    floatx4 acc[4][4];
#pragma unroll
    for (int i = 0; i < 4; ++i)
#pragma unroll
        for (int j = 0; j < 4; ++j) acc[i][j] = (floatx4){0.f, 0.f, 0.f, 0.f};

    auto compute = [&](int buf) {
        short8 af[4], bv[4];
#pragma unroll
        for (int mf = 0; mf < 4; ++mf) {
            const int r = mf * 16 + l16;
            af[mf] = *(const short8*)&As[buf][r * 32 + ((lq ^ (r & 3)) << 3)];
        }
#pragma unroll
        for (int nf = 0; nf < 4; ++nf) {
            const int r = wave * 64 + nf * 16 + l16;
            bv[nf] = *(const short8*)&Bs[buf][r * 32 + ((lq ^ (r & 3)) << 3)];
        }
#pragma unroll
        for (int mf = 0; mf < 4; ++mf)
#pragma unroll
            for (int nf = 0; nf < 4; ++nf)
                acc[mf][nf] = __builtin_amdgcn_mfma_f32_16x16x32_bf16(
                    bv[nf], af[mf], acc[mf][nf], 0, 0, 0);   // swapped -> C^T frag
    };

    // --- prologue: B(0) DMA first (oldest), A(0)+A(1) to regs, write A(0) ---
    stageB(0, 0);
    loadA(0, 0);
    loadA(1, 1);
    writeA(0, 0);                       // compiler waits A(0) loads only
    wait_vm_lgkm0<VM>();                // drain B-DMA(0); A(1) stays in flight
    __builtin_amdgcn_s_barrier();
    __builtin_amdgcn_sched_barrier(0);

    // --- K loop: steps 0..6 stage next, step 7 compute-only ---
#pragma unroll
    for (int k = 0; k < 7; ++k) {
        const int cur = k & 1, nxt = cur ^ 1;
        stageB(k + 1, nxt);             // 4 DMAs, issued first (oldest)
        if (k < 6) loadA(k + 2, k & 1); // 2-step-ahead A prefetch
        compute(cur);
        writeA(nxt, (k + 1) & 1);       // compiler auto-waits A(k+1) (landed)
        if (k < 6) wait_vm_lgkm0<VM>(); // drain B-DMAs, keep A(k+2) in flight
        else       wait_vm_lgkm0<0>();  // nothing left to protect
        __builtin_amdgcn_s_barrier();
        __builtin_amdgcn_sched_barrier(0);
    }
    compute(1);                          // k=7

    // --- epilogue: row-major vector stores ---
#pragma unroll
    for (int mf = 0; mf < 4; ++mf) {
        const long grow = row0 + mf * 16 + l16;
#pragma unroll
        for (int nf = 0; nf < 4; ++nf) {
            const int gcol = wave * 64 + nf * 16 + lq * 4;
            const floatx4 bv4 = *(const floatx4*)(bias + gcol);
            const floatx4 v = acc[mf][nf] + bv4;
            if (OUT_F32) {
                *(floatx4*)((float*)Cv + grow * 256 + gcol) = v;
            } else {
                bfx4 s;
#pragma unroll
                for (int r = 0; r < 4; ++r) s[r] = (short)f2bf(v[r]);
                *(bfx4*)((short*)Cv + grow * 256 + gcol) = s;
            }
        }
    }
}

// ---------------------------------------------------------------------------
// gemm_tile (round-4 structure, kept for the 384-col offattn GEMM)
// ---------------------------------------------------------------------------
template<int NW, int A_BF16, int OUT_F32>
__global__ __launch_bounds__(NW * 128) void gemm_tile(
        const void* __restrict__ Av, const short* __restrict__ Bt,
        const float* __restrict__ bias, void* __restrict__ Cv, int Ntot) {
    constexpr int NT = NW * 128;
    constexpr int BN = NW * 64;
    constexpr int AIT = (512 + NT - 1) / NT;
    __shared__ short As[2][128 * 32];
    __shared__ short Bs[2][BN * 32];

    const int tid  = threadIdx.x;
    const int lane = tid & 63, wave = tid >> 6;
    const int l16  = lane & 15, lq = lane >> 4;
    const int wr   = wave / NW, wc = wave % NW;
    const long row0 = (long)blockIdx.x * 128;
    const int  col0 = blockIdx.y * BN;

    floatx4 acc[4][4];
#pragma unroll
    for (int i = 0; i < 4; ++i)
#pragma unroll
        for (int j = 0; j < 4; ++j) acc[i][j] = (floatx4){0.f, 0.f, 0.f, 0.f};

    floatx4 a0[AIT], a1[AIT];

    auto loadA = [&](int kk) {
#pragma unroll
        for (int it = 0; it < AIT; ++it) {
            const int i = tid + it * NT;
            if (i < 512) {
                const int r = i >> 2, c = i & 3;
                const float* g = (const float*)Av + (row0 + r) * 256 + kk * 32 + c * 8;
                a0[it] = *(const floatx4*)g;
                a1[it] = *(const floatx4*)(g + 4);
            }
        }
    };
    auto writeA = [&](int bb) {
#pragma unroll
        for (int it = 0; it < AIT; ++it) {
            const int i = tid + it * NT;
            if (i < 512) {
                const int r = i >> 2, c = i & 3;
                short8 v;
#pragma unroll
                for (int j = 0; j < 4; ++j) {
                    v[j]     = (short)f2bf(a0[it][j]);
                    v[4 + j] = (short)f2bf(a1[it][j]);
                }
                *(short8*)&As[bb][r * 32 + ((c ^ (r & 3)) << 3)] = v;
            }
        }
    };
    auto stageB = [&](int kk, int bb) {
#pragma unroll
        for (int c2 = 0; c2 < 2; ++c2) {
            const int idx = c2 * NT + tid;
            const int r = idx >> 2, ch = idx & 3;
            const short* g = Bt + (long)(col0 + r) * 256 + kk * 32 + ((ch ^ (r & 3)) << 3);
            async16(&Bs[bb][(c2 * NT + (wave << 6)) * 8], g);
        }
    };

    loadA(0);
    stageB(0, 0);
    writeA(0);
    __syncthreads();

    int buf = 0;
    for (int kk = 0; kk < 8; ++kk) {
        const int nxt = buf ^ 1;
        if (kk < 7) {
            loadA(kk + 1);
            stageB(kk + 1, nxt);
        }
        short8 af[4], bv[4];
#pragma unroll
        for (int mf = 0; mf < 4; ++mf) {
            const int r = wr * 64 + mf * 16 + l16;
            af[mf] = *(const short8*)&As[buf][r * 32 + ((lq ^ (r & 3)) << 3)];
        }
#pragma unroll
        for (int nf = 0; nf < 4; ++nf) {
            const int r = wc * 64 + nf * 16 + l16;
            bv[nf] = *(const short8*)&Bs[buf][r * 32 + ((lq ^ (r & 3)) << 3)];
        }
#pragma unroll
        for (int mf = 0; mf < 4; ++mf)
#pragma unroll
            for (int nf = 0; nf < 4; ++nf)
                acc[mf][nf] = __builtin_amdgcn_mfma_f32_16x16x32_bf16(af[mf], bv[nf], acc[mf][nf], 0, 0, 0);
        if (kk < 7) writeA(nxt);
        __syncthreads();
        buf = nxt;
    }

#pragma unroll
    for (int nf = 0; nf < 4; ++nf) {
        const int col = col0 + wc * 64 + nf * 16 + l16;
        const float bvl = bias[col];
#pragma unroll
        for (int mf = 0; mf < 4; ++mf)
#pragma unroll
            for (int r = 0; r < 4; ++r) {
                const long row = row0 + wr * 64 + mf * 16 + lq * 4 + r;
                const float v = acc[mf][nf][r] + bvl;
                if (OUT_F32) ((float*)Cv)[row * Ntot + col] = v;
                else         ((short*)Cv)[row * Ntot + col] = (short)f2bf(v);
            }
    }
}

// ---------------------------------------------------------------------------
// Sampler: softmax + deformable bilinear gather -> wv (bf16)
// Branchless corners, per-level batched loads (16 x 16B in flight).
// 512 threads, 16 queries per block. Grid = B * (Q/16) = 512.
// ---------------------------------------------------------------------------
__global__ __launch_bounds__(512) void sampler(
        const float* __restrict__ priors,
        const int* __restrict__ shapes, const int* __restrict__ starts,
        const float* __restrict__ offattn,   // [B*Q][384]: 256 off | 128 attn logits
        const short* __restrict__ value, short* __restrict__ wv) {
    __shared__ float oa_lds[16][384];
    __shared__ float pri_lds[16][4][2];
    __shared__ int   shp_lds[4][2];
    __shared__ int   st_lds[4];

    const int tid = threadIdx.x;
    const int b   = blockIdx.x >> 7;
    const int qt  = blockIdx.x & 127;
    const long q0 = (long)qt * 16;

    const float* src = offattn + ((long)b * Qn_ + q0) * 384;
    for (int i = tid; i < 16 * 384 / 4; i += 512)
        ((floatx4*)oa_lds)[i] = ((const floatx4*)src)[i];
    if (tid < 128) ((float*)pri_lds)[tid] = priors[((long)b * Qn_ + q0) * 8 + tid];
    if (tid < 8)  ((int*)shp_lds)[tid] = shapes[tid];
    if (tid < 4)  st_lds[tid] = starts[tid];
    __syncthreads();

    if (tid < 128) {
        const int qi = tid >> 3, h = tid & 7;
        float* a = &oa_lds[qi][256 + h * 16];
        float m = a[0];
        for (int i = 1; i < 16; ++i) m = fmaxf(m, a[i]);
        float s = 0.f;
        for (int i = 0; i < 16; ++i) { float e = expf(a[i] - m); a[i] = e; s += e; }
        const float inv = 1.f / s;
        for (int i = 0; i < 16; ++i) a[i] *= inv;
    }
    __syncthreads();

    const int pairi = tid >> 2, sub = tid & 3;
    const int qi = pairi >> 3, h = pairi & 7;
    float acc[8];
#pragma unroll
    for (int j = 0; j < 8; ++j) acc[j] = 0.f;
    const short* vbase = value + (long)b * S_ * 256 + h * 32 + sub * 8;

    for (int l = 0; l < 4; ++l) {
        const int Hl = shp_lds[l][0], Wl = shp_lds[l][1];
        const int st = st_lds[l];
        const float px = pri_lds[qi][l][0], py = pri_lds[qi][l][1];
        const float invW = 1.f / (float)Wl, invH = 1.f / (float)Hl;

        float wgt[16];
        int   off[16];
#pragma unroll
        for (int p = 0; p < 4; ++p) {
            const int cb = h * 16 + l * 4 + p;
            const float ox = oa_lds[qi][cb * 2], oy = oa_lds[qi][cb * 2 + 1];
            const float lx = px + ox * invW, ly = py + oy * invH;
            const float ix = lx * (float)Wl - 0.5f, iy = ly * (float)Hl - 0.5f;
            const float x0f = floorf(ix), y0f = floorf(iy);
            const int x0 = (int)x0f, y0 = (int)y0f;
            const float fx = ix - x0f, fy = iy - y0f;
            const float awv = oa_lds[qi][256 + cb];
#pragma unroll
            for (int dy = 0; dy < 2; ++dy) {
                const int yc = y0 + dy;
                const float wy = dy ? fy : 1.f - fy;
                const int yi = min(max(yc, 0), Hl - 1);
#pragma unroll
                for (int dx = 0; dx < 2; ++dx) {
                    const int xc = x0 + dx;
                    const float wx = dx ? fx : 1.f - fx;
                    const int xi = min(max(xc, 0), Wl - 1);
                    const bool v = (xc >= 0) & (xc < Wl) & (yc >= 0) & (yc < Hl);
                    const int j = p * 4 + dy * 2 + dx;
                    wgt[j] = v ? wy * wx * awv : 0.f;
                    off[j] = yi * Wl + xi;
                }
            }
        }
        const short* base = vbase + (long)st * 256;
        short8 vv[16];
#pragma unroll
        for (int j = 0; j < 16; ++j)
            vv[j] = *(const short8*)(base + (long)off[j] * 256);
#pragma unroll
        for (int j = 0; j < 16; ++j) {
            const float w = wgt[j];
#pragma unroll
            for (int c = 0; c < 8; ++c) acc[c] += w * bf2f((unsigned short)vv[j][c]);
        }
    }

    short8 ov;
#pragma unroll
    for (int j = 0; j < 8; ++j) ov[j] = (short)f2bf(acc[j]);
    *(short8*)(wv + (((long)b * Qn_ + q0 + qi) * 256 + h * 32 + sub * 8)) = ov;
}

// ---------------------------------------------------------------------------
extern "C" void kernel_launch(void* const* d_in, const int* in_sizes, int n_in,
                              void* d_out, int out_size, void* d_ws, size_t ws_size,
                              hipStream_t stream) {
    const float* in_feats = (const float*)d_in[0];
    const float* priors   = (const float*)d_in[1];
    const float* sfeats   = (const float*)d_in[2];
    const int*   shapes   = (const int*)d_in[3];
    const int*   starts   = (const int*)d_in[4];
    const float* W_off    = (const float*)d_in[5];
    const float* b_off    = (const float*)d_in[6];
    const float* W_attn   = (const float*)d_in[7];
    const float* b_attn   = (const float*)d_in[8];
    const float* W_val    = (const float*)d_in[9];
    const float* b_val    = (const float*)d_in[10];
    const float* W_out    = (const float*)d_in[11];
    const float* b_out    = (const float*)d_in[12];
    float* out = (float*)d_out;

    // Workspace: Wvt 128K | Wot 128K | Wcat 192K | value 44.56M | wv 4M (short)
    //            offattn 12.58M | bcat 1.5K (f32)
    short* Wvt     = (short*)d_ws;
    short* Wot     = Wvt + 65536;
    short* Wcat    = Wot + 65536;
    short* value   = Wcat + 98304;
    short* wv      = value + (long)B_ * S_ * 256;
    float* offattn = (float*)(wv + (long)B_ * Qn_ * 256);
    float* bcat    = offattn + (long)B_ * Qn_ * 384;

    prep_w<<<256, 896, 0, stream>>>(W_val, W_out, W_off, W_attn, b_off, b_attn,
                                    Wvt, Wot, Wcat, bcat);
    // value = sample_feats @ W_val + b_val   (87040 x 256), bf16 out
    gemm_v8<0, 0><<<(B_ * S_) / 64, 256, 0, stream>>>(
        (const void*)sfeats, Wvt, b_val, (void*)value);
    // offattn = in_feats @ [W_off|W_attn] + bcat  (8192 x 384), f32 out
    gemm_tile<3, 0, 1><<<dim3((B_ * Qn_) / 128, 2), 384, 0, stream>>>(
        (const void*)in_feats, Wcat, bcat, (void*)offattn, 384);
    // softmax + deformable sampling
    sampler<<<B_ * (Qn_ / 16), 512, 0, stream>>>(priors, shapes, starts,
                                                 offattn, value, wv);
    // out = wv @ W_out + b_out   (8192 x 256), f32 out
    gemm_v8<1, 1><<<(B_ * Qn_) / 64, 256, 0, stream>>>(
        (const void*)wv, Wot, b_out, (void*)out);
}

// Round 9
// 94.841 us; speedup vs baseline: 1.6641x; 1.0159x over previous
//
#include <hip/hip_runtime.h>
#include <hip/hip_bf16.h>

// Problem constants (fixed by reference)
#define B_    4
#define Qn_   2048
#define S_    21760   // 128*128 + 64*64 + 32*32 + 16*16

typedef short  bfx4    __attribute__((ext_vector_type(4)));
typedef short  short8  __attribute__((ext_vector_type(8)));
typedef float  floatx4 __attribute__((ext_vector_type(4)));

__device__ __forceinline__ unsigned short f2bf(float f) {
    unsigned int u = __builtin_bit_cast(unsigned int, f);
    u += 0x7fffu + ((u >> 16) & 1u);   // round-to-nearest-even
    return (unsigned short)(u >> 16);
}
__device__ __forceinline__ float bf2f(unsigned short h) {
    unsigned int u = ((unsigned int)h) << 16;
    return __builtin_bit_cast(float, u);
}

// packed f32x8 -> bf16x8 via v_cvt_pk_bf16_f32 (RNE, 1 instr / 2 elems)
__device__ __forceinline__ short8 cvt_pk8(floatx4 f0, floatx4 f1) {
    union { unsigned int u[4]; short8 s; } r;
    asm("v_cvt_pk_bf16_f32 %0, %1, %2" : "=v"(r.u[0]) : "v"(f0[0]), "v"(f0[1]));
    asm("v_cvt_pk_bf16_f32 %0, %1, %2" : "=v"(r.u[1]) : "v"(f0[2]), "v"(f0[3]));
    asm("v_cvt_pk_bf16_f32 %0, %1, %2" : "=v"(r.u[2]) : "v"(f1[0]), "v"(f1[1]));
    asm("v_cvt_pk_bf16_f32 %0, %1, %2" : "=v"(r.u[3]) : "v"(f1[2]), "v"(f1[3]));
    return r.s;
}

// async global->LDS, 16B per lane. lds must be WAVE-UNIFORM base (lane*16 implicit).
__device__ __forceinline__ void async16(void* lds, const void* g) {
    __builtin_amdgcn_global_load_lds(
        (const __attribute__((address_space(1))) unsigned int*)g,
        (__attribute__((address_space(3))) unsigned int*)lds, 16, 0, 0);
}

template<int N>
__device__ __forceinline__ void wait_vm_lgkm0() {
    asm volatile("s_waitcnt vmcnt(%0) lgkmcnt(0)" :: "n"(N) : "memory");
}

// ---------------------------------------------------------------------------
// Prep: cast+transpose weights to bf16 NxK, concat off|attn, concat biases.
// ---------------------------------------------------------------------------
__global__ __launch_bounds__(896) void prep_w(
        const float* __restrict__ Wv, const float* __restrict__ Wo,
        const float* __restrict__ Woff, const float* __restrict__ Wattn,
        const float* __restrict__ boff, const float* __restrict__ battn,
        short* __restrict__ Wvt, short* __restrict__ Wot,
        short* __restrict__ Wcat, float* __restrict__ bcat) {
    const int k = blockIdx.x;      // 0..255
    const int t = threadIdx.x;
    if (t < 256) {
        Wvt[t * 256 + k] = (short)f2bf(Wv[k * 256 + t]);
    } else if (t < 512) {
        const int n = t - 256;
        Wot[n * 256 + k] = (short)f2bf(Wo[k * 256 + n]);
    } else {
        const int n = t - 512;     // 0..383
        const float w = (n < 256) ? Woff[k * 256 + n] : Wattn[k * 128 + (n - 256)];
        Wcat[n * 256 + k] = (short)f2bf(w);
    }
    if (blockIdx.x == 0 && t < 384)
        bcat[t] = (t < 256) ? boff[t] : battn[t - 256];
}

// ---------------------------------------------------------------------------
// gemm_v9: C[M x 256] = A[M x 256](f32) @ B[256 x 256] + bias -> bf16.
//   BM=128, BN=256, 8 waves (2 row-halves x 4 col-quarters, wave = 64x64).
//   2-phase K-loop (8 x BK=32), T4 counted-vmcnt barriers:
//     per step: stageB (2 DMA/thread, oldest) -> loadA(k+2) (2 loads) ->
//     compute -> writeA(k+1) (cvt_pk, compiler waits A(k+1) only) ->
//     vmcnt(2): drains B-DMAs, A(k+2) stays in flight across the barrier.
//   LDS 48 KB; __launch_bounds__(512,4) caps VGPR at 128 -> 2-3 blocks/CU.
//   LDS [r][32] bf16 rows, 16B-chunk XOR swizzle (chunk ^= r&3), rule #21.
//   MFMA swapped -> row-major bf16x4 stores.
// ---------------------------------------------------------------------------
__global__ __launch_bounds__(512, 4) void gemm_v9(
        const float* __restrict__ Av, const short* __restrict__ Bt,
        const float* __restrict__ bias, short* __restrict__ Cv) {
    __shared__ short As[2][128 * 32];    // 16 KB
    __shared__ short Bs[2][256 * 32];    // 32 KB

    const int tid  = threadIdx.x;
    const int lane = tid & 63, wave = tid >> 6;
    const int l16  = lane & 15, lq = lane >> 4;
    const int wr   = wave >> 2, wc = wave & 3;
    const long row0 = (long)blockIdx.x * 128;
    const int  r_a = tid >> 2, c_a = tid & 3;   // A-stage chunk: (row, 16B-chunk)

    floatx4 sA0[2], sA1[2];

    auto loadA = [&](int kk, int s) {
        const float* g = Av + (row0 + r_a) * 256 + kk * 32 + c_a * 8;
        sA0[s] = *(const floatx4*)g;
        sA1[s] = *(const floatx4*)(g + 4);
    };
    auto writeA = [&](int buf, int s) {
        *(short8*)&As[buf][r_a * 32 + ((c_a ^ (r_a & 3)) << 3)] = cvt_pk8(sA0[s], sA1[s]);
    };
    auto stageB = [&](int kk, int buf) {
#pragma unroll
        for (int c2 = 0; c2 < 2; ++c2) {
            const int idx = c2 * 512 + tid;
            const int r = idx >> 2, ch = idx & 3;
            const short* g = Bt + (long)r * 256 + kk * 32 + ((ch ^ (r & 3)) << 3);
            async16(&Bs[buf][(c2 * 512 + (wave << 6)) * 8], g);
        }
    };

    floatx4 acc[4][4];
#pragma unroll
    for (int i = 0; i < 4; ++i)
#pragma unroll
        for (int j = 0; j < 4; ++j) acc[i][j] = (floatx4){0.f, 0.f, 0.f, 0.f};

    auto compute = [&](int buf) {
        short8 af[4], bv[4];
#pragma unroll
        for (int mf = 0; mf < 4; ++mf) {
            const int r = wr * 64 + mf * 16 + l16;
            af[mf] = *(const short8*)&As[buf][r * 32 + ((lq ^ (r & 3)) << 3)];
        }
#pragma unroll
        for (int nf = 0; nf < 4; ++nf) {
            const int r = wc * 64 + nf * 16 + l16;
            bv[nf] = *(const short8*)&Bs[buf][r * 32 + ((lq ^ (r & 3)) << 3)];
        }
#pragma unroll
        for (int mf = 0; mf < 4; ++mf)
#pragma unroll
            for (int nf = 0; nf < 4; ++nf)
                acc[mf][nf] = __builtin_amdgcn_mfma_f32_16x16x32_bf16(
                    bv[nf], af[mf], acc[mf][nf], 0, 0, 0);   // swapped -> C^T frag
    };

    // --- prologue ---
    stageB(0, 0);
    loadA(0, 0);
    loadA(1, 1);
    writeA(0, 0);                        // compiler drains B(0)+A(0); A(1) flies
    wait_vm_lgkm0<2>();
    __builtin_amdgcn_s_barrier();
    __builtin_amdgcn_sched_barrier(0);

    // --- K loop: steps 0..6 stage next, step 7 compute-only ---
#pragma unroll
    for (int k = 0; k < 7; ++k) {
        const int cur = k & 1, nxt = cur ^ 1;
        stageB(k + 1, nxt);              // 2 DMAs, issued first (oldest)
        if (k < 6) loadA(k + 2, k & 1);  // 2-step-ahead A prefetch
        compute(cur);
        writeA(nxt, (k + 1) & 1);        // compiler auto-waits A(k+1) (landed)
        if (k < 6) wait_vm_lgkm0<2>();   // drain B-DMAs, keep A(k+2) in flight
        else       wait_vm_lgkm0<0>();
        __builtin_amdgcn_s_barrier();
        __builtin_amdgcn_sched_barrier(0);
    }
    compute(1);                           // kk=7

    // --- epilogue: row-major bf16x4 stores ---
#pragma unroll
    for (int mf = 0; mf < 4; ++mf) {
        const long grow = row0 + wr * 64 + mf * 16 + l16;
#pragma unroll
        for (int nf = 0; nf < 4; ++nf) {
            const int gcol = wc * 64 + nf * 16 + lq * 4;
            const floatx4 bv4 = *(const floatx4*)(bias + gcol);
            const floatx4 v = acc[mf][nf] + bv4;
            bfx4 s;
#pragma unroll
            for (int r = 0; r < 4; ++r) s[r] = (short)f2bf(v[r]);
            *(bfx4*)(Cv + grow * 256 + gcol) = s;
        }
    }
}

// ---------------------------------------------------------------------------
// gemm_v8 (round-8, kept unchanged for the out GEMM)
// ---------------------------------------------------------------------------
template<int A_BF16, int OUT_F32>
__global__ __launch_bounds__(256) void gemm_v8(
        const void* __restrict__ Av, const short* __restrict__ Bt,
        const float* __restrict__ bias, void* __restrict__ Cv) {
    constexpr int VM = A_BF16 ? 1 : 2;
    __shared__ short As[2][64 * 32];
    __shared__ short Bs[2][256 * 32];

    const int tid  = threadIdx.x;
    const int lane = tid & 63, wave = tid >> 6;
    const int l16  = lane & 15, lq = lane >> 4;
    const long row0 = (long)blockIdx.x * 64;
    const int  r_a = tid >> 2, c_a = tid & 3;

    floatx4 sA0[2], sA1[2];
    short8  sB16[2];

    auto loadA = [&](int kk, int s) {
        if (A_BF16) {
            sB16[s] = *(const short8*)((const short*)Av + (row0 + r_a) * 256 + kk * 32 + c_a * 8);
        } else {
            const float* g = (const float*)Av + (row0 + r_a) * 256 + kk * 32 + c_a * 8;
            sA0[s] = *(const floatx4*)g;
            sA1[s] = *(const floatx4*)(g + 4);
        }
    };
    auto writeA = [&](int buf, int s) {
        short8 v;
        if (A_BF16) v = sB16[s];
        else        v = cvt_pk8(sA0[s], sA1[s]);
        *(short8*)&As[buf][r_a * 32 + ((c_a ^ (r_a & 3)) << 3)] = v;
    };
    auto stageB = [&](int kk, int buf) {
#pragma unroll
        for (int c2 = 0; c2 < 4; ++c2) {
            const int idx = c2 * 256 + tid;
            const int r = idx >> 2, ch = idx & 3;
            const short* g = Bt + (long)r * 256 + kk * 32 + ((ch ^ (r & 3)) << 3);
            async16(&Bs[buf][(c2 * 256 + (wave << 6)) * 8], g);
        }
    };

    floatx4 acc[4][4];
#pragma unroll
    for (int i = 0; i < 4; ++i)
#pragma unroll
        for (int j = 0; j < 4; ++j) acc[i][j] = (floatx4){0.f, 0.f, 0.f, 0.f};

    auto compute = [&](int buf) {
        short8 af[4], bv[4];
#pragma unroll
        for (int mf = 0; mf < 4; ++mf) {
            const int r = mf * 16 + l16;
            af[mf] = *(const short8*)&As[buf][r * 32 + ((lq ^ (r & 3)) << 3)];
        }
#pragma unroll
        for (int nf = 0; nf < 4; ++nf) {
            const int r = wave * 64 + nf * 16 + l16;
            bv[nf] = *(const short8*)&Bs[buf][r * 32 + ((lq ^ (r & 3)) << 3)];
        }
#pragma unroll
        for (int mf = 0; mf < 4; ++mf)
#pragma unroll
            for (int nf = 0; nf < 4; ++nf)
                acc[mf][nf] = __builtin_amdgcn_mfma_f32_16x16x32_bf16(
                    bv[nf], af[mf], acc[mf][nf], 0, 0, 0);
    };

    stageB(0, 0);
    loadA(0, 0);
    loadA(1, 1);
    writeA(0, 0);
    wait_vm_lgkm0<VM>();
    __builtin_amdgcn_s_barrier();
    __builtin_amdgcn_sched_barrier(0);

#pragma unroll
    for (int k = 0; k < 7; ++k) {
        const int cur = k & 1, nxt = cur ^ 1;
        stageB(k + 1, nxt);
        if (k < 6) loadA(k + 2, k & 1);
        compute(cur);
        writeA(nxt, (k + 1) & 1);
        if (k < 6) wait_vm_lgkm0<VM>();
        else       wait_vm_lgkm0<0>();
        __builtin_amdgcn_s_barrier();
        __builtin_amdgcn_sched_barrier(0);
    }
    compute(1);

#pragma unroll
    for (int mf = 0; mf < 4; ++mf) {
        const long grow = row0 + mf * 16 + l16;
#pragma unroll
        for (int nf = 0; nf < 4; ++nf) {
            const int gcol = wave * 64 + nf * 16 + lq * 4;
            const floatx4 bv4 = *(const floatx4*)(bias + gcol);
            const floatx4 v = acc[mf][nf] + bv4;
            if (OUT_F32) {
                *(floatx4*)((float*)Cv + grow * 256 + gcol) = v;
            } else {
                bfx4 s;
#pragma unroll
                for (int r = 0; r < 4; ++r) s[r] = (short)f2bf(v[r]);
                *(bfx4*)((short*)Cv + grow * 256 + gcol) = s;
            }
        }
    }
}

// ---------------------------------------------------------------------------
// gemm_tile (round-4 structure, kept for the 384-col offattn GEMM)
// ---------------------------------------------------------------------------
template<int NW, int A_BF16, int OUT_F32>
__global__ __launch_bounds__(NW * 128) void gemm_tile(
        const void* __restrict__ Av, const short* __restrict__ Bt,
        const float* __restrict__ bias, void* __restrict__ Cv, int Ntot) {
    constexpr int NT = NW * 128;
    constexpr int BN = NW * 64;
    constexpr int AIT = (512 + NT - 1) / NT;
    __shared__ short As[2][128 * 32];
    __shared__ short Bs[2][BN * 32];

    const int tid  = threadIdx.x;
    const int lane = tid & 63, wave = tid >> 6;
    const int l16  = lane & 15, lq = lane >> 4;
    const int wr   = wave / NW, wc = wave % NW;
    const long row0 = (long)blockIdx.x * 128;
    const int  col0 = blockIdx.y * BN;

    floatx4 acc[4][4];
#pragma unroll
    for (int i = 0; i < 4; ++i)
#pragma unroll
        for (int j = 0; j < 4; ++j) acc[i][j] = (floatx4){0.f, 0.f, 0.f, 0.f};

    floatx4 a0[AIT], a1[AIT];

    auto loadA = [&](int kk) {
#pragma unroll
        for (int it = 0; it < AIT; ++it) {
            const int i = tid + it * NT;
            if (i < 512) {
                const int r = i >> 2, c = i & 3;
                const float* g = (const float*)Av + (row0 + r) * 256 + kk * 32 + c * 8;
                a0[it] = *(const floatx4*)g;
                a1[it] = *(const floatx4*)(g + 4);
            }
        }
    };
    auto writeA = [&](int bb) {
#pragma unroll
        for (int it = 0; it < AIT; ++it) {
            const int i = tid + it * NT;
            if (i < 512) {
                const int r = i >> 2, c = i & 3;
                *(short8*)&As[bb][r * 32 + ((c ^ (r & 3)) << 3)] = cvt_pk8(a0[it], a1[it]);
            }
        }
    };
    auto stageB = [&](int kk, int bb) {
#pragma unroll
        for (int c2 = 0; c2 < 2; ++c2) {
            const int idx = c2 * NT + tid;
            const int r = idx >> 2, ch = idx & 3;
            const short* g = Bt + (long)(col0 + r) * 256 + kk * 32 + ((ch ^ (r & 3)) << 3);
            async16(&Bs[bb][(c2 * NT + (wave << 6)) * 8], g);
        }
    };

    loadA(0);
    stageB(0, 0);
    writeA(0);
    __syncthreads();

    int buf = 0;
    for (int kk = 0; kk < 8; ++kk) {
        const int nxt = buf ^ 1;
        if (kk < 7) {
            loadA(kk + 1);
            stageB(kk + 1, nxt);
        }
        short8 af[4], bv[4];
#pragma unroll
        for (int mf = 0; mf < 4; ++mf) {
            const int r = wr * 64 + mf * 16 + l16;
            af[mf] = *(const short8*)&As[buf][r * 32 + ((lq ^ (r & 3)) << 3)];
        }
#pragma unroll
        for (int nf = 0; nf < 4; ++nf) {
            const int r = wc * 64 + nf * 16 + l16;
            bv[nf] = *(const short8*)&Bs[buf][r * 32 + ((lq ^ (r & 3)) << 3)];
        }
#pragma unroll
        for (int mf = 0; mf < 4; ++mf)
#pragma unroll
            for (int nf = 0; nf < 4; ++nf)
                acc[mf][nf] = __builtin_amdgcn_mfma_f32_16x16x32_bf16(af[mf], bv[nf], acc[mf][nf], 0, 0, 0);
        if (kk < 7) writeA(nxt);
        __syncthreads();
        buf = nxt;
    }

#pragma unroll
    for (int nf = 0; nf < 4; ++nf) {
        const int col = col0 + wc * 64 + nf * 16 + l16;
        const float bvl = bias[col];
#pragma unroll
        for (int mf = 0; mf < 4; ++mf)
#pragma unroll
            for (int r = 0; r < 4; ++r) {
                const long row = row0 + wr * 64 + mf * 16 + lq * 4 + r;
                const float v = acc[mf][nf][r] + bvl;
                if (OUT_F32) ((float*)Cv)[row * Ntot + col] = v;
                else         ((short*)Cv)[row * Ntot + col] = (short)f2bf(v);
            }
    }
}

// ---------------------------------------------------------------------------
// Sampler: softmax + deformable bilinear gather -> wv (bf16)  (round-8)
// ---------------------------------------------------------------------------
__global__ __launch_bounds__(512) void sampler(
        const float* __restrict__ priors,
        const int* __restrict__ shapes, const int* __restrict__ starts,
        const float* __restrict__ offattn,
        const short* __restrict__ value, short* __restrict__ wv) {
    __shared__ float oa_lds[16][384];
    __shared__ float pri_lds[16][4][2];
    __shared__ int   shp_lds[4][2];
    __shared__ int   st_lds[4];

    const int tid = threadIdx.x;
    const int b   = blockIdx.x >> 7;
    const int qt  = blockIdx.x & 127;
    const long q0 = (long)qt * 16;

    const float* src = offattn + ((long)b * Qn_ + q0) * 384;
    for (int i = tid; i < 16 * 384 / 4; i += 512)
        ((floatx4*)oa_lds)[i] = ((const floatx4*)src)[i];
    if (tid < 128) ((float*)pri_lds)[tid] = priors[((long)b * Qn_ + q0) * 8 + tid];
    if (tid < 8)  ((int*)shp_lds)[tid] = shapes[tid];
    if (tid < 4)  st_lds[tid] = starts[tid];
    __syncthreads();

    if (tid < 128) {
        const int qi = tid >> 3, h = tid & 7;
        float* a = &oa_lds[qi][256 + h * 16];
        float m = a[0];
        for (int i = 1; i < 16; ++i) m = fmaxf(m, a[i]);
        float s = 0.f;
        for (int i = 0; i < 16; ++i) { float e = expf(a[i] - m); a[i] = e; s += e; }
        const float inv = 1.f / s;
        for (int i = 0; i < 16; ++i) a[i] *= inv;
    }
    __syncthreads();

    const int pairi = tid >> 2, sub = tid & 3;
    const int qi = pairi >> 3, h = pairi & 7;
    float acc[8];
#pragma unroll
    for (int j = 0; j < 8; ++j) acc[j] = 0.f;
    const short* vbase = value + (long)b * S_ * 256 + h * 32 + sub * 8;

    for (int l = 0; l < 4; ++l) {
        const int Hl = shp_lds[l][0], Wl = shp_lds[l][1];
        const int st = st_lds[l];
        const float px = pri_lds[qi][l][0], py = pri_lds[qi][l][1];
        const float invW = 1.f / (float)Wl, invH = 1.f / (float)Hl;

        float wgt[16];
        int   off[16];
#pragma unroll
        for (int p = 0; p < 4; ++p) {
            const int cb = h * 16 + l * 4 + p;
            const float ox = oa_lds[qi][cb * 2], oy = oa_lds[qi][cb * 2 + 1];
            const float lx = px + ox * invW, ly = py + oy * invH;
            const float ix = lx * (float)Wl - 0.5f, iy = ly * (float)Hl - 0.5f;
            const float x0f = floorf(ix), y0f = floorf(iy);
            const int x0 = (int)x0f, y0 = (int)y0f;
            const float fx = ix - x0f, fy = iy - y0f;
            const float awv = oa_lds[qi][256 + cb];
#pragma unroll
            for (int dy = 0; dy < 2; ++dy) {
                const int yc = y0 + dy;
                const float wy = dy ? fy : 1.f - fy;
                const int yi = min(max(yc, 0), Hl - 1);
#pragma unroll
                for (int dx = 0; dx < 2; ++dx) {
                    const int xc = x0 + dx;
                    const float wx = dx ? fx : 1.f - fx;
                    const int xi = min(max(xc, 0), Wl - 1);
                    const bool v = (xc >= 0) & (xc < Wl) & (yc >= 0) & (yc < Hl);
                    const int j = p * 4 + dy * 2 + dx;
                    wgt[j] = v ? wy * wx * awv : 0.f;
                    off[j] = yi * Wl + xi;
                }
            }
        }
        const short* base = vbase + (long)st * 256;
        short8 vv[16];
#pragma unroll
        for (int j = 0; j < 16; ++j)
            vv[j] = *(const short8*)(base + (long)off[j] * 256);
#pragma unroll
        for (int j = 0; j < 16; ++j) {
            const float w = wgt[j];
#pragma unroll
            for (int c = 0; c < 8; ++c) acc[c] += w * bf2f((unsigned short)vv[j][c]);
        }
    }

    short8 ov;
#pragma unroll
    for (int j = 0; j < 8; ++j) ov[j] = (short)f2bf(acc[j]);
    *(short8*)(wv + (((long)b * Qn_ + q0 + qi) * 256 + h * 32 + sub * 8)) = ov;
}

// ---------------------------------------------------------------------------
extern "C" void kernel_launch(void* const* d_in, const int* in_sizes, int n_in,
                              void* d_out, int out_size, void* d_ws, size_t ws_size,
                              hipStream_t stream) {
    const float* in_feats = (const float*)d_in[0];
    const float* priors   = (const float*)d_in[1];
    const float* sfeats   = (const float*)d_in[2];
    const int*   shapes   = (const int*)d_in[3];
    const int*   starts   = (const int*)d_in[4];
    const float* W_off    = (const float*)d_in[5];
    const float* b_off    = (const float*)d_in[6];
    const float* W_attn   = (const float*)d_in[7];
    const float* b_attn   = (const float*)d_in[8];
    const float* W_val    = (const float*)d_in[9];
    const float* b_val    = (const float*)d_in[10];
    const float* W_out    = (const float*)d_in[11];
    const float* b_out    = (const float*)d_in[12];
    float* out = (float*)d_out;

    // Workspace: Wvt 128K | Wot 128K | Wcat 192K | value 44.56M | wv 4M (short)
    //            offattn 12.58M | bcat 1.5K (f32)
    short* Wvt     = (short*)d_ws;
    short* Wot     = Wvt + 65536;
    short* Wcat    = Wot + 65536;
    short* value   = Wcat + 98304;
    short* wv      = value + (long)B_ * S_ * 256;
    float* offattn = (float*)(wv + (long)B_ * Qn_ * 256);
    float* bcat    = offattn + (long)B_ * Qn_ * 384;

    prep_w<<<256, 896, 0, stream>>>(W_val, W_out, W_off, W_attn, b_off, b_attn,
                                    Wvt, Wot, Wcat, bcat);
    // value = sample_feats @ W_val + b_val   (87040 x 256), bf16 out
    gemm_v9<<<(B_ * S_) / 128, 512, 0, stream>>>(sfeats, Wvt, b_val, value);
    // offattn = in_feats @ [W_off|W_attn] + bcat  (8192 x 384), f32 out
    gemm_tile<3, 0, 1><<<dim3((B_ * Qn_) / 128, 2), 384, 0, stream>>>(
        (const void*)in_feats, Wcat, bcat, (void*)offattn, 384);
    // softmax + deformable sampling
    sampler<<<B_ * (Qn_ / 16), 512, 0, stream>>>(priors, shapes, starts,
                                                 offattn, value, wv);
    // out = wv @ W_out + b_out   (8192 x 256), f32 out
    gemm_v8<1, 1><<<(B_ * Qn_) / 64, 256, 0, stream>>>(
        (const void*)wv, Wot, b_out, (void*)out);
}